// Round 1
// baseline (5483.253 us; speedup 1.0000x reference)
//
#include <hip/hip_runtime.h>

#define BB 1024
#define TT 128
#define DIN 256
#define HH 128
#define G4 512   // 4*H
#define NBLK 256

using bf16   = __bf16;
using bf16x8 = __attribute__((ext_vector_type(8))) bf16;
using bf16x4 = __attribute__((ext_vector_type(4))) bf16;
using f32x4  = __attribute__((ext_vector_type(4))) float;

__device__ __forceinline__ float sigmoidf_(float x) { return 1.f / (1.f + __expf(-x)); }

// ---------------------------------------------------------------------------
// prep_a: column softmax of memory, bias, G0 (rv0 @ Wrv^T), zero h, zero barrier
// ---------------------------------------------------------------------------
__global__ void prep_a(const float* __restrict__ mem, const float* __restrict__ b_ih,
                       const float* __restrict__ b_hh, const float* __restrict__ rv0,
                       const float* __restrict__ W_ih,
                       float* __restrict__ mem_sm, float* __restrict__ bias,
                       float* __restrict__ G0, bf16* __restrict__ hbuf,
                       unsigned* __restrict__ bar) {
  const int bid = blockIdx.x, tid = threadIdx.x;
  if (bid == 0) {
    if (tid < 128) {  // softmax over axis 0 (rows m) for column tid
      float mx = -1e30f;
      for (int m = 0; m < 128; ++m) mx = fmaxf(mx, mem[m * 128 + tid]);
      float s = 0.f;
      for (int m = 0; m < 128; ++m) s += __expf(mem[m * 128 + tid] - mx);
      float inv = 1.f / s;
      for (int m = 0; m < 128; ++m) mem_sm[m * 128 + tid] = __expf(mem[m * 128 + tid] - mx) * inv;
    }
  } else if (bid == 1) {
    for (int e = tid; e < G4; e += 256) bias[e] = b_ih[e] + b_hh[e];
  } else if (bid < 4) {
    int g = (bid - 2) * 256 + tid;  // 0..511
    float acc = 0.f;
    for (int k = 0; k < 512; ++k) acc += rv0[k] * W_ih[g * 768 + 256 + k];
    G0[g] = acc;
  } else {
    if (bid == 4 && tid < 4) bar[tid] = 0u;
    unsigned* hz = (unsigned*)hbuf;  // 1024*128 bf16 = 65536 dwords
    for (int i = (bid - 4) * 256 + tid; i < 65536; i += 64 * 256) hz[i] = 0u;
  }
}

// ---------------------------------------------------------------------------
// prep_b: WM = Wrv-chunks @ mem_sm (bf16), FM = fc_w-chunks @ mem_sm (f32),
//         x f32 [B,T,256] -> bf16 [T,B,256]
// ---------------------------------------------------------------------------
__global__ void prep_b(const float* __restrict__ x, const float* __restrict__ W_ih,
                       const float* __restrict__ fc_w, const float* __restrict__ mem_sm,
                       bf16* __restrict__ WMg, float* __restrict__ FM,
                       bf16* __restrict__ x_bf) {
  const int bid = blockIdx.x, tid = threadIdx.x;
  if (bid < 128) {
    for (int sub = tid; sub < 4 * 512; sub += 256) {
      int gl = sub >> 9, rn = sub & 511, r = rn >> 7, n = rn & 127;
      int g = bid * 4 + gl;
      const float* wr = W_ih + g * 768 + 256 + r * 128;
      float acc = 0.f;
      for (int m = 0; m < 128; ++m) acc += wr[m] * mem_sm[m * 128 + n];
      WMg[(size_t)g * 512 + rn] = (bf16)acc;
    }
  } else if (bid == 128) {
    for (int sub = tid; sub < 2 * 512; sub += 256) {
      int o = sub >> 9, rn = sub & 511, r = rn >> 7, n = rn & 127;
      const float* wr = fc_w + o * 640 + 128 + r * 128;
      float acc = 0.f;
      for (int m = 0; m < 128; ++m) acc += wr[m] * mem_sm[m * 128 + n];
      FM[o * 512 + rn] = acc;
    }
  } else {
    const int lane = tid & 63, wv = tid >> 6;
    for (int rep = 0; rep < 128; ++rep) {
      int rid = (bid - 129) * 512 + wv * 128 + rep;   // rid = b*T + t
      int b = rid >> 7, t = rid & 127;
      const float4 v = *(const float4*)(x + (size_t)rid * 256 + lane * 4);
      bf16x4 o;
      o[0] = (bf16)v.x; o[1] = (bf16)v.y; o[2] = (bf16)v.z; o[3] = (bf16)v.w;
      *(bf16x4*)(x_bf + ((size_t)t * BB + b) * 256 + lane * 4) = o;
    }
  }
}

// ---------------------------------------------------------------------------
// custom device-scope grid barrier (256 blocks, all co-resident: 1/CU)
// ---------------------------------------------------------------------------
__device__ __forceinline__ void gridbar(unsigned* bar, unsigned gen) {
  __syncthreads();
  if (threadIdx.x == 0) {
    __threadfence();  // release: drain + L2 writeback (agent scope)
    unsigned arr = __hip_atomic_fetch_add(bar, 1u, __ATOMIC_RELAXED, __HIP_MEMORY_SCOPE_AGENT) + 1u;
    if (arr == gen * (unsigned)NBLK) {
      __hip_atomic_store(bar + 1, gen, __ATOMIC_RELAXED, __HIP_MEMORY_SCOPE_AGENT);
    } else {
      while (__hip_atomic_load(bar + 1, __ATOMIC_RELAXED, __HIP_MEMORY_SCOPE_AGENT) < gen)
        __builtin_amdgcn_s_sleep(1);
    }
    __threadfence();  // acquire: invalidate stale L1/L2
  }
  __syncthreads();
}

// ---------------------------------------------------------------------------
// persistent main kernel: 256 blocks x 256 threads, weights LDS-resident
//   block (rt,gt): rt=bid>>4 row-tile (64 batch rows), gt=bid&15 (32 gate cols)
//   M phase: gp[rows,cols] = bias + x_{t+1}@Wx^T + h_t@Whh^T ; G = hquad@WM^T
//   P phase: block bid owns batch rows [4*bid,4*bid+4): LSTM pointwise,
//            c/hsum LDS-resident across all 128 steps.
// ---------------------------------------------------------------------------
__global__ void __launch_bounds__(256, 1) dnc_main(
    const bf16* __restrict__ x_bf, const bf16* __restrict__ WMg,
    const float* __restrict__ bias, const float* __restrict__ G0,
    const float* __restrict__ FM, bf16* __restrict__ hbuf,
    float* __restrict__ gp, float* __restrict__ Gbuf, float* __restrict__ hsumG,
    unsigned* __restrict__ bar,
    const float* __restrict__ W_ih, const float* __restrict__ W_hh,
    const float* __restrict__ fc_w, const float* __restrict__ fc_b,
    float* __restrict__ out) {
  __shared__ bf16 sWx[32][264];    // Wx  g-tile, K=256, +8 pad
  __shared__ bf16 sWhh[32][136];   // Whh g-tile, K=128, +8 pad
  __shared__ bf16 sWM[32][520];    // WM  g-tile, K=512, +8 pad
  __shared__ float sC[4][128];     // cell state, rows 4*bid..+4
  __shared__ float sH[4][128];     // running sum of h over t

  const int bid = blockIdx.x, tid = threadIdx.x;
  const int rt = bid >> 4, gt = bid & 15;
  const int g0 = gt * 32;
  const int wave = tid >> 6, lane = tid & 63;
  const int l15 = lane & 15, l4 = lane >> 4;

  // one-time weight staging into LDS (f32 -> bf16 for Wx/Whh; WM already bf16)
  for (int e = tid; e < 32 * 256; e += 256) sWx[e >> 8][e & 255] = (bf16)W_ih[(g0 + (e >> 8)) * 768 + (e & 255)];
  for (int e = tid; e < 32 * 128; e += 256) sWhh[e >> 7][e & 127] = (bf16)W_hh[(g0 + (e >> 7)) * 128 + (e & 127)];
  for (int e = tid; e < 32 * 512; e += 256) sWM[e >> 9][e & 511] = WMg[(size_t)(g0 + (e >> 9)) * 512 + (e & 511)];
  for (int e = tid; e < 512; e += 256) { sC[e >> 7][e & 127] = 0.f; sH[e >> 7][e & 127] = 0.f; }
  __syncthreads();

  const float bv0 = bias[g0 + l15], bv1 = bias[g0 + 16 + l15];
  unsigned gen = 0;

  auto do_M = [&](int tnext) {
    // gates GEMM: m-subtile = wave (16 rows), 2 n-subtiles of 16
    const int mbase = rt * 64 + wave * 16;
    f32x4 acc0 = {bv0, bv0, bv0, bv0};
    f32x4 acc1 = {bv1, bv1, bv1, bv1};
    const bf16* xr = x_bf + ((size_t)tnext * BB + (mbase + l15)) * DIN + l4 * 8;
#pragma unroll
    for (int kk = 0; kk < 8; ++kk) {   // K = 256 (x part)
      bf16x8 a  = *(const bf16x8*)(xr + kk * 32);
      bf16x8 w0 = *(const bf16x8*)&sWx[l15][kk * 32 + l4 * 8];
      bf16x8 w1 = *(const bf16x8*)&sWx[16 + l15][kk * 32 + l4 * 8];
      acc0 = __builtin_amdgcn_mfma_f32_16x16x32_bf16(a, w0, acc0, 0, 0, 0);
      acc1 = __builtin_amdgcn_mfma_f32_16x16x32_bf16(a, w1, acc1, 0, 0, 0);
    }
    const bf16* hr = hbuf + (size_t)(mbase + l15) * HH + l4 * 8;
#pragma unroll
    for (int kk = 0; kk < 4; ++kk) {   // K = 128 (h part)
      bf16x8 a  = *(const bf16x8*)(hr + kk * 32);
      bf16x8 w0 = *(const bf16x8*)&sWhh[l15][kk * 32 + l4 * 8];
      bf16x8 w1 = *(const bf16x8*)&sWhh[16 + l15][kk * 32 + l4 * 8];
      acc0 = __builtin_amdgcn_mfma_f32_16x16x32_bf16(a, w0, acc0, 0, 0, 0);
      acc1 = __builtin_amdgcn_mfma_f32_16x16x32_bf16(a, w1, acc1, 0, 0, 0);
    }
    // C/D layout: row = l4*4+reg, col = l15
    float* gpo = gp + (size_t)(mbase + l4 * 4) * G4 + g0 + l15;
#pragma unroll
    for (int r = 0; r < 4; ++r) {
      gpo[r * G4]      = acc0[r];
      gpo[r * G4 + 16] = acc1[r];
    }
    // G GEMM: 16 j-rows (= hquad rows, contiguous reinterpret of h), waves 0/1
    if (wave < 2) {
      const bf16* hq = hbuf + (size_t)(rt * 16 + l15) * 512 + l4 * 8;
      f32x4 ga = {0.f, 0.f, 0.f, 0.f};
#pragma unroll
      for (int kk = 0; kk < 16; ++kk) {  // K = 512
        bf16x8 a = *(const bf16x8*)(hq + kk * 32);
        bf16x8 w = *(const bf16x8*)&sWM[wave * 16 + l15][kk * 32 + l4 * 8];
        ga = __builtin_amdgcn_mfma_f32_16x16x32_bf16(a, w, ga, 0, 0, 0);
      }
      float* go = Gbuf + (size_t)(rt * 16 + l4 * 4) * G4 + g0 + wave * 16 + l15;
#pragma unroll
      for (int r = 0; r < 4; ++r) go[r * G4] = ga[r];
    }
  };

  auto do_P = [&](int t) {
#pragma unroll
    for (int it = 0; it < 2; ++it) {
      int item = tid + it * 256;          // 0..511
      int rl = item >> 7, n = item & 127;
      int row = bid * 4 + rl;
      const float* gpr = gp + (size_t)row * G4;
      float gi = gpr[n], gf = gpr[128 + n], gg = gpr[256 + n], go_ = gpr[384 + n];
      if (t == 0) {
        gi += G0[n]; gf += G0[128 + n]; gg += G0[256 + n]; go_ += G0[384 + n];
      } else {
        const float* Gr = Gbuf + (size_t)(row & 255) * G4;
        gi += Gr[n]; gf += Gr[128 + n]; gg += Gr[256 + n]; go_ += Gr[384 + n];
      }
      float cn = sigmoidf_(gf) * sC[rl][n] + sigmoidf_(gi) * tanhf(gg);
      float hn = sigmoidf_(go_) * tanhf(cn);
      sC[rl][n] = cn;
      sH[rl][n] += hn;
      hbuf[(size_t)row * HH + n] = (bf16)hn;
    }
  };

  // timeline: M(-1) fills gp for t=0 (h=0 pre-zeroed; G path at t=0 uses G0)
  do_M(0);
  for (int t = 0; t < TT; ++t) {
    gridbar(bar, ++gen);   // gp_t (and G_t) visible
    do_P(t);
    if (t < TT - 1) {
      gridbar(bar, ++gen); // h_t visible
      do_M(t + 1);
    }
  }
  // epilogue: out = (hsum @ fc_w_h^T + hquadsum @ FM^T)/T + fc_b
#pragma unroll
  for (int it = 0; it < 2; ++it) {
    int item = tid + it * 256;
    int rl = item >> 7, n = item & 127;
    hsumG[(size_t)(bid * 4 + rl) * HH + n] = sH[rl][n];
  }
  gridbar(bar, ++gen);
  {
    int row = bid * 4 + wave;
    const float* hs = hsumG + (size_t)row * HH;
    const float* hq = hsumG + (size_t)(row & 255) * 512;
    float s0 = 0.f, s1 = 0.f;
    for (int k = lane; k < 128; k += 64) { float v = hs[k]; s0 += v * fc_w[k]; s1 += v * fc_w[640 + k]; }
    for (int k = lane; k < 512; k += 64) { float v = hq[k]; s0 += v * FM[k]; s1 += v * FM[512 + k]; }
    for (int off = 32; off > 0; off >>= 1) { s0 += __shfl_down(s0, off); s1 += __shfl_down(s1, off); }
    if (lane == 0) {
      out[row * 2 + 0] = s0 * (1.f / 128.f) + fc_b[0];
      out[row * 2 + 1] = s1 * (1.f / 128.f) + fc_b[1];
    }
  }
}

// ---------------------------------------------------------------------------
extern "C" void kernel_launch(void* const* d_in, const int* in_sizes, int n_in,
                              void* d_out, int out_size, void* d_ws, size_t ws_size,
                              hipStream_t stream) {
  const float* x      = (const float*)d_in[0];
  const float* memory = (const float*)d_in[1];
  const float* rv0    = (const float*)d_in[2];
  const float* W_ih   = (const float*)d_in[3];
  const float* W_hh   = (const float*)d_in[4];
  const float* b_ih   = (const float*)d_in[5];
  const float* b_hh   = (const float*)d_in[6];
  const float* fc_w   = (const float*)d_in[7];
  const float* fc_b   = (const float*)d_in[8];
  float* out = (float*)d_out;
  char* ws = (char*)d_ws;

  bf16*     x_bf   = (bf16*)ws;                     // 67,108,864 B
  bf16*     WMg    = (bf16*)(ws + 67108864);        //    524,288
  float*    mem_sm = (float*)(ws + 67633152);       //     65,536
  float*    bias   = (float*)(ws + 67698688);       //      2,048
  float*    G0     = (float*)(ws + 67700736);       //      2,048
  float*    FM     = (float*)(ws + 67702784);       //      4,096
  bf16*     hbuf   = (bf16*)(ws + 67706880);        //    262,144
  float*    gp     = (float*)(ws + 67969024);       //  2,097,152
  float*    Gbuf   = (float*)(ws + 70066176);       //    524,288
  float*    hsumG  = (float*)(ws + 70590464);       //    524,288
  unsigned* bar    = (unsigned*)(ws + 71114752);    //         16

  prep_a<<<68, 256, 0, stream>>>(memory, b_ih, b_hh, rv0, W_ih, mem_sm, bias, G0, hbuf, bar);
  prep_b<<<385, 256, 0, stream>>>(x, W_ih, fc_w, mem_sm, WMg, FM, x_bf);
  dnc_main<<<NBLK, 256, 0, stream>>>(x_bf, WMg, bias, G0, FM, hbuf, gp, Gbuf, hsumG, bar,
                                     W_ih, W_hh, fc_w, fc_b, out);
}

// Round 2
// 2703.823 us; speedup vs baseline: 2.0280x; 2.0280x over previous
//
#include <hip/hip_runtime.h>

#define BB 1024
#define TT 128
#define DIN 256
#define HH 128
#define G4 512   // 4*H
#define NBLK 256

using bf16   = __bf16;
using bf16x8 = __attribute__((ext_vector_type(8))) bf16;
using bf16x4 = __attribute__((ext_vector_type(4))) bf16;
using f32x4  = __attribute__((ext_vector_type(4))) float;

__device__ __forceinline__ float sigmoidf_(float x) { return 1.f / (1.f + __expf(-x)); }

// ---- coherent (cross-XCD, Infinity-Cache-served) load/store helpers --------
__device__ __forceinline__ void st_f32_coh(float* p, float v) {
  __hip_atomic_store(p, v, __ATOMIC_RELAXED, __HIP_MEMORY_SCOPE_AGENT);
}
__device__ __forceinline__ float ld_f32_coh(const float* p) {
  return __hip_atomic_load((float*)p, __ATOMIC_RELAXED, __HIP_MEMORY_SCOPE_AGENT);
}
__device__ __forceinline__ float2 ld_f32x2_coh(const float* p) {
  unsigned long long u = __hip_atomic_load((unsigned long long*)p, __ATOMIC_RELAXED,
                                           __HIP_MEMORY_SCOPE_AGENT);
  union { unsigned long long u; float2 f; } c; c.u = u; return c.f;
}
__device__ __forceinline__ void st_u32_coh(unsigned* p, unsigned v) {
  __hip_atomic_store(p, v, __ATOMIC_RELAXED, __HIP_MEMORY_SCOPE_AGENT);
}
__device__ __forceinline__ bf16x8 ld_bf16x8_coh(const bf16* p) {
  union { unsigned long long u[2]; bf16x8 v; } c;
  c.u[0] = __hip_atomic_load((unsigned long long*)p, __ATOMIC_RELAXED, __HIP_MEMORY_SCOPE_AGENT);
  c.u[1] = __hip_atomic_load((unsigned long long*)(p + 4), __ATOMIC_RELAXED, __HIP_MEMORY_SCOPE_AGENT);
  return c.v;
}

// ---------------------------------------------------------------------------
// prep_a: column softmax of memory, bias, G0 (rv0 @ Wrv^T), zero h, zero barrier
// ---------------------------------------------------------------------------
__global__ void prep_a(const float* __restrict__ mem, const float* __restrict__ b_ih,
                       const float* __restrict__ b_hh, const float* __restrict__ rv0,
                       const float* __restrict__ W_ih,
                       float* __restrict__ mem_sm, float* __restrict__ bias,
                       float* __restrict__ G0, bf16* __restrict__ hbuf,
                       unsigned* __restrict__ bar) {
  const int bid = blockIdx.x, tid = threadIdx.x;
  if (bid == 0) {
    if (tid < 128) {  // softmax over axis 0 (rows m) for column tid
      float mx = -1e30f;
      for (int m = 0; m < 128; ++m) mx = fmaxf(mx, mem[m * 128 + tid]);
      float s = 0.f;
      for (int m = 0; m < 128; ++m) s += __expf(mem[m * 128 + tid] - mx);
      float inv = 1.f / s;
      for (int m = 0; m < 128; ++m) mem_sm[m * 128 + tid] = __expf(mem[m * 128 + tid] - mx) * inv;
    }
  } else if (bid == 1) {
    for (int e = tid; e < G4; e += 256) bias[e] = b_ih[e] + b_hh[e];
  } else if (bid < 4) {
    int g = (bid - 2) * 256 + tid;  // 0..511
    float acc = 0.f;
    for (int k = 0; k < 512; ++k) acc += rv0[k] * W_ih[g * 768 + 256 + k];
    G0[g] = acc;
  } else {
    if (bid == 4 && tid < 4) bar[tid] = 0u;
    unsigned* hz = (unsigned*)hbuf;  // 1024*128 bf16 = 65536 dwords
    for (int i = (bid - 4) * 256 + tid; i < 65536; i += 64 * 256) hz[i] = 0u;
  }
}

// ---------------------------------------------------------------------------
// prep_b: WM = Wrv-chunks @ mem_sm (bf16), FM = fc_w-chunks @ mem_sm (f32),
//         x f32 [B,T,256] -> bf16 [T,B,256]
// ---------------------------------------------------------------------------
__global__ void prep_b(const float* __restrict__ x, const float* __restrict__ W_ih,
                       const float* __restrict__ fc_w, const float* __restrict__ mem_sm,
                       bf16* __restrict__ WMg, float* __restrict__ FM,
                       bf16* __restrict__ x_bf) {
  const int bid = blockIdx.x, tid = threadIdx.x;
  if (bid < 128) {
    for (int sub = tid; sub < 4 * 512; sub += 256) {
      int gl = sub >> 9, rn = sub & 511, r = rn >> 7, n = rn & 127;
      int g = bid * 4 + gl;
      const float* wr = W_ih + g * 768 + 256 + r * 128;
      float acc = 0.f;
      for (int m = 0; m < 128; ++m) acc += wr[m] * mem_sm[m * 128 + n];
      WMg[(size_t)g * 512 + rn] = (bf16)acc;
    }
  } else if (bid == 128) {
    for (int sub = tid; sub < 2 * 512; sub += 256) {
      int o = sub >> 9, rn = sub & 511, r = rn >> 7, n = rn & 127;
      const float* wr = fc_w + o * 640 + 128 + r * 128;
      float acc = 0.f;
      for (int m = 0; m < 128; ++m) acc += wr[m] * mem_sm[m * 128 + n];
      FM[o * 512 + rn] = acc;
    }
  } else {
    const int lane = tid & 63, wv = tid >> 6;
    for (int rep = 0; rep < 128; ++rep) {
      int rid = (bid - 129) * 512 + wv * 128 + rep;   // rid = b*T + t
      int b = rid >> 7, t = rid & 127;
      const float4 v = *(const float4*)(x + (size_t)rid * 256 + lane * 4);
      bf16x4 o;
      o[0] = (bf16)v.x; o[1] = (bf16)v.y; o[2] = (bf16)v.z; o[3] = (bf16)v.w;
      *(bf16x4*)(x_bf + ((size_t)t * BB + b) * 256 + lane * 4) = o;
    }
  }
}

// ---------------------------------------------------------------------------
// fence-free grid barrier: all cross-block data uses sc0/sc1 write-through ops,
// and __syncthreads() drains each wave's vmcnt, so no L2 wb/inv is needed.
// ---------------------------------------------------------------------------
__device__ __forceinline__ void gridbar(unsigned* bar, unsigned gen) {
  asm volatile("s_waitcnt vmcnt(0)" ::: "memory");
  __syncthreads();
  if (threadIdx.x == 0) {
    unsigned arr = __hip_atomic_fetch_add(bar, 1u, __ATOMIC_RELAXED, __HIP_MEMORY_SCOPE_AGENT) + 1u;
    if (arr == gen * (unsigned)NBLK) {
      __hip_atomic_store(bar + 1, gen, __ATOMIC_RELAXED, __HIP_MEMORY_SCOPE_AGENT);
    } else {
      while (__hip_atomic_load(bar + 1, __ATOMIC_RELAXED, __HIP_MEMORY_SCOPE_AGENT) < gen)
        __builtin_amdgcn_s_sleep(1);
    }
  }
  __syncthreads();
}

// ---------------------------------------------------------------------------
// persistent main kernel: 256 blocks x 256 threads, weights LDS-resident
// ---------------------------------------------------------------------------
__global__ void __launch_bounds__(256, 1) dnc_main(
    const bf16* __restrict__ x_bf, const bf16* __restrict__ WMg,
    const float* __restrict__ bias, const float* __restrict__ G0,
    const float* __restrict__ FM, bf16* __restrict__ hbuf,
    float* __restrict__ gp, float* __restrict__ Gbuf, float* __restrict__ hsumG,
    unsigned* __restrict__ bar,
    const float* __restrict__ W_ih, const float* __restrict__ W_hh,
    const float* __restrict__ fc_w, const float* __restrict__ fc_b,
    float* __restrict__ out) {
  __shared__ bf16 sWx[32][264];    // Wx  g-tile, K=256, +8 pad
  __shared__ bf16 sWhh[32][136];   // Whh g-tile, K=128, +8 pad
  __shared__ bf16 sWM[32][520];    // WM  g-tile, K=512, +8 pad
  __shared__ float sC[4][128];     // cell state, rows 4*bid..+4
  __shared__ float sH[4][128];     // running sum of h over t

  const int bid = blockIdx.x, tid = threadIdx.x;
  const int rt = bid >> 4, gt = bid & 15;
  const int g0 = gt * 32;
  const int wave = tid >> 6, lane = tid & 63;
  const int l15 = lane & 15, l4 = lane >> 4;

  // one-time weight staging into LDS (f32 -> bf16 for Wx/Whh; WM already bf16)
  for (int e = tid; e < 32 * 256; e += 256) sWx[e >> 8][e & 255] = (bf16)W_ih[(g0 + (e >> 8)) * 768 + (e & 255)];
  for (int e = tid; e < 32 * 128; e += 256) sWhh[e >> 7][e & 127] = (bf16)W_hh[(g0 + (e >> 7)) * 128 + (e & 127)];
  for (int e = tid; e < 32 * 512; e += 256) sWM[e >> 9][e & 511] = WMg[(size_t)(g0 + (e >> 9)) * 512 + (e & 511)];
  for (int e = tid; e < 512; e += 256) { sC[e >> 7][e & 127] = 0.f; sH[e >> 7][e & 127] = 0.f; }
  __syncthreads();

  const float bv0 = bias[g0 + l15], bv1 = bias[g0 + 16 + l15];
  unsigned gen = 0;

  auto do_M = [&](int tnext) {
    // gates GEMM: m-subtile = wave (16 rows), 2 n-subtiles of 16
    const int mbase = rt * 64 + wave * 16;
    f32x4 acc0 = {bv0, bv0, bv0, bv0};
    f32x4 acc1 = {bv1, bv1, bv1, bv1};
    const bf16* xr = x_bf + ((size_t)tnext * BB + (mbase + l15)) * DIN + l4 * 8;
#pragma unroll
    for (int kk = 0; kk < 8; ++kk) {   // K = 256 (x part, plain cached loads)
      bf16x8 a  = *(const bf16x8*)(xr + kk * 32);
      bf16x8 w0 = *(const bf16x8*)&sWx[l15][kk * 32 + l4 * 8];
      bf16x8 w1 = *(const bf16x8*)&sWx[16 + l15][kk * 32 + l4 * 8];
      acc0 = __builtin_amdgcn_mfma_f32_16x16x32_bf16(a, w0, acc0, 0, 0, 0);
      acc1 = __builtin_amdgcn_mfma_f32_16x16x32_bf16(a, w1, acc1, 0, 0, 0);
    }
    const bf16* hr = hbuf + (size_t)(mbase + l15) * HH + l4 * 8;
#pragma unroll
    for (int kk = 0; kk < 4; ++kk) {   // K = 128 (h part, coherent loads)
      bf16x8 a  = ld_bf16x8_coh(hr + kk * 32);
      bf16x8 w0 = *(const bf16x8*)&sWhh[l15][kk * 32 + l4 * 8];
      bf16x8 w1 = *(const bf16x8*)&sWhh[16 + l15][kk * 32 + l4 * 8];
      acc0 = __builtin_amdgcn_mfma_f32_16x16x32_bf16(a, w0, acc0, 0, 0, 0);
      acc1 = __builtin_amdgcn_mfma_f32_16x16x32_bf16(a, w1, acc1, 0, 0, 0);
    }
    // C/D layout: row = l4*4+reg, col = l15
    float* gpo = gp + (size_t)(mbase + l4 * 4) * G4 + g0 + l15;
#pragma unroll
    for (int r = 0; r < 4; ++r) {
      st_f32_coh(gpo + r * G4, acc0[r]);
      st_f32_coh(gpo + r * G4 + 16, acc1[r]);
    }
    // G GEMM: 16 j-rows (= hquad rows, contiguous reinterpret of h), waves 0/1
    if (wave < 2) {
      const bf16* hq = hbuf + (size_t)(rt * 16 + l15) * 512 + l4 * 8;
      f32x4 ga = {0.f, 0.f, 0.f, 0.f};
#pragma unroll
      for (int kk = 0; kk < 16; ++kk) {  // K = 512
        bf16x8 a = ld_bf16x8_coh(hq + kk * 32);
        bf16x8 w = *(const bf16x8*)&sWM[wave * 16 + l15][kk * 32 + l4 * 8];
        ga = __builtin_amdgcn_mfma_f32_16x16x32_bf16(a, w, ga, 0, 0, 0);
      }
      float* go = Gbuf + (size_t)(rt * 16 + l4 * 4) * G4 + g0 + wave * 16 + l15;
#pragma unroll
      for (int r = 0; r < 4; ++r) st_f32_coh(go + r * G4, ga[r]);
    }
  };

  auto do_P = [&](int t) {
    // 256 threads x 2 adjacent columns = 512 items (4 rows x 128 cols)
    const int item = tid * 2;
    const int rl = item >> 7, n = item & 127;   // n even
    const int row = bid * 4 + rl;
    const float* gpr = gp + (size_t)row * G4;
    float2 vi = ld_f32x2_coh(gpr + n);
    float2 vf = ld_f32x2_coh(gpr + 128 + n);
    float2 vg = ld_f32x2_coh(gpr + 256 + n);
    float2 vo = ld_f32x2_coh(gpr + 384 + n);
    float2 ai, af, ag, ao;
    if (t == 0) {
      ai = *(const float2*)(G0 + n);        af = *(const float2*)(G0 + 128 + n);
      ag = *(const float2*)(G0 + 256 + n);  ao = *(const float2*)(G0 + 384 + n);
    } else {
      const float* Gr = Gbuf + (size_t)(row & 255) * G4;
      ai = ld_f32x2_coh(Gr + n);        af = ld_f32x2_coh(Gr + 128 + n);
      ag = ld_f32x2_coh(Gr + 256 + n);  ao = ld_f32x2_coh(Gr + 384 + n);
    }
    float hn[2];
#pragma unroll
    for (int j = 0; j < 2; ++j) {
      float gi = (j ? vi.y + ai.y : vi.x + ai.x);
      float gf = (j ? vf.y + af.y : vf.x + af.x);
      float gg = (j ? vg.y + ag.y : vg.x + ag.x);
      float go_ = (j ? vo.y + ao.y : vo.x + ao.x);
      float cn = sigmoidf_(gf) * sC[rl][n + j] + sigmoidf_(gi) * tanhf(gg);
      hn[j] = sigmoidf_(go_) * tanhf(cn);
      sC[rl][n + j] = cn;
      sH[rl][n + j] += hn[j];
    }
    union { bf16 h[2]; unsigned u; } pk;
    pk.h[0] = (bf16)hn[0]; pk.h[1] = (bf16)hn[1];
    st_u32_coh((unsigned*)(hbuf + (size_t)row * HH + n), pk.u);
  };

  // timeline: M(-1) fills gp for t=0 (h=0 pre-zeroed; G path at t=0 uses G0)
  do_M(0);
  for (int t = 0; t < TT; ++t) {
    gridbar(bar, ++gen);   // gp_t (and G_t) visible
    do_P(t);
    if (t < TT - 1) {
      gridbar(bar, ++gen); // h_t visible
      do_M(t + 1);
    }
  }
  // epilogue: out = (hsum @ fc_w_h^T + hquadsum @ FM^T)/T + fc_b
#pragma unroll
  for (int it = 0; it < 2; ++it) {
    int item = tid + it * 256;
    int rl = item >> 7, n = item & 127;
    st_f32_coh(hsumG + (size_t)(bid * 4 + rl) * HH + n, sH[rl][n]);
  }
  gridbar(bar, ++gen);
  {
    int row = bid * 4 + wave;
    const float* hs = hsumG + (size_t)row * HH;
    const float* hq = hsumG + (size_t)(row & 255) * 512;
    float s0 = 0.f, s1 = 0.f;
    for (int k = lane; k < 128; k += 64) { float v = ld_f32_coh(hs + k); s0 += v * fc_w[k]; s1 += v * fc_w[640 + k]; }
    for (int k = lane; k < 512; k += 64) { float v = ld_f32_coh(hq + k); s0 += v * FM[k]; s1 += v * FM[512 + k]; }
    for (int off = 32; off > 0; off >>= 1) { s0 += __shfl_down(s0, off); s1 += __shfl_down(s1, off); }
    if (lane == 0) {
      out[row * 2 + 0] = s0 * (1.f / 128.f) + fc_b[0];
      out[row * 2 + 1] = s1 * (1.f / 128.f) + fc_b[1];
    }
  }
}

// ---------------------------------------------------------------------------
extern "C" void kernel_launch(void* const* d_in, const int* in_sizes, int n_in,
                              void* d_out, int out_size, void* d_ws, size_t ws_size,
                              hipStream_t stream) {
  const float* x      = (const float*)d_in[0];
  const float* memory = (const float*)d_in[1];
  const float* rv0    = (const float*)d_in[2];
  const float* W_ih   = (const float*)d_in[3];
  const float* W_hh   = (const float*)d_in[4];
  const float* b_ih   = (const float*)d_in[5];
  const float* b_hh   = (const float*)d_in[6];
  const float* fc_w   = (const float*)d_in[7];
  const float* fc_b   = (const float*)d_in[8];
  float* out = (float*)d_out;
  char* ws = (char*)d_ws;

  bf16*     x_bf   = (bf16*)ws;                     // 67,108,864 B
  bf16*     WMg    = (bf16*)(ws + 67108864);        //    524,288
  float*    mem_sm = (float*)(ws + 67633152);       //     65,536
  float*    bias   = (float*)(ws + 67698688);       //      2,048
  float*    G0     = (float*)(ws + 67700736);       //      2,048
  float*    FM     = (float*)(ws + 67702784);       //      4,096
  bf16*     hbuf   = (bf16*)(ws + 67706880);        //    262,144
  float*    gp     = (float*)(ws + 67969024);       //  2,097,152
  float*    Gbuf   = (float*)(ws + 70066176);       //    524,288
  float*    hsumG  = (float*)(ws + 70590464);       //    524,288
  unsigned* bar    = (unsigned*)(ws + 71114752);    //         16

  prep_a<<<68, 256, 0, stream>>>(memory, b_ih, b_hh, rv0, W_ih, mem_sm, bias, G0, hbuf, bar);
  prep_b<<<385, 256, 0, stream>>>(x, W_ih, fc_w, mem_sm, WMg, FM, x_bf);
  dnc_main<<<NBLK, 256, 0, stream>>>(x_bf, WMg, bias, G0, FM, hbuf, gp, Gbuf, hsumG, bar,
                                     W_ih, W_hh, fc_w, fc_b, out);
}

// Round 3
// 1010.667 us; speedup vs baseline: 5.4254x; 2.6753x over previous
//
#include <hip/hip_runtime.h>

#define BB 1024
#define TT 128
#define NBLK 256

using bf16   = __bf16;
using bf16x8 = __attribute__((ext_vector_type(8))) bf16;
using bf16x4 = __attribute__((ext_vector_type(4))) bf16;
using f32x4  = __attribute__((ext_vector_type(4))) float;

__device__ __forceinline__ float sigmoidf_(float x) { return 1.f / (1.f + __expf(-x)); }

// ---- coherent (cross-XCD, IF$-served) load/store helpers -------------------
__device__ __forceinline__ void st_u32_coh(unsigned* p, unsigned v) {
  __hip_atomic_store(p, v, __ATOMIC_RELAXED, __HIP_MEMORY_SCOPE_AGENT);
}
__device__ __forceinline__ unsigned ld_u32_coh(const unsigned* p) {
  return __hip_atomic_load((unsigned*)p, __ATOMIC_RELAXED, __HIP_MEMORY_SCOPE_AGENT);
}
__device__ __forceinline__ float ld_f32_coh(const float* p) {
  return __hip_atomic_load((float*)p, __ATOMIC_RELAXED, __HIP_MEMORY_SCOPE_AGENT);
}
__device__ __forceinline__ void st_f32x2_coh(float* p, float a, float b) {
  union { float f[2]; unsigned long long u; } c; c.f[0] = a; c.f[1] = b;
  __hip_atomic_store((unsigned long long*)p, c.u, __ATOMIC_RELAXED, __HIP_MEMORY_SCOPE_AGENT);
}
__device__ __forceinline__ bf16x8 ld_bf16x8_coh(const bf16* p) {
  union { unsigned long long u[2]; bf16x8 v; } c;
  c.u[0] = __hip_atomic_load((unsigned long long*)p, __ATOMIC_RELAXED, __HIP_MEMORY_SCOPE_AGENT);
  c.u[1] = __hip_atomic_load((unsigned long long*)(p + 4), __ATOMIC_RELAXED, __HIP_MEMORY_SCOPE_AGENT);
  return c.v;
}

// ---------------------------------------------------------------------------
// prep_a: column softmax of memory (via LDS), bias, G0 = rv0 @ Wrv^T, zero slots
// ---------------------------------------------------------------------------
__global__ void prep_a(const float* __restrict__ mem, const float* __restrict__ b_ih,
                       const float* __restrict__ b_hh, const float* __restrict__ rv0,
                       const float* __restrict__ W_ih,
                       float* __restrict__ mem_sm, float* __restrict__ bias,
                       float* __restrict__ G0, unsigned* __restrict__ slots) {
  const int bid = blockIdx.x, tid = threadIdx.x;
  if (bid == 0) {
    __shared__ float sM[128 * 128];
    for (int e = tid; e < 16384; e += 256) sM[e] = mem[e];
    __syncthreads();
    if (tid < 128) {
      float mx = -1e30f;
      for (int m = 0; m < 128; ++m) mx = fmaxf(mx, sM[m * 128 + tid]);
      float s = 0.f;
      for (int m = 0; m < 128; ++m) s += __expf(sM[m * 128 + tid] - mx);
      float inv = 1.f / s;
      for (int m = 0; m < 128; ++m) mem_sm[m * 128 + tid] = __expf(sM[m * 128 + tid] - mx) * inv;
    }
  } else if (bid == 1) {
    for (int e = tid; e < 512; e += 256) bias[e] = b_ih[e] + b_hh[e];
  } else if (bid < 4) {
    int g = (bid - 2) * 256 + tid;  // 0..511
    float acc = 0.f;
    for (int k = 0; k < 512; ++k) acc += rv0[k] * W_ih[(size_t)g * 768 + 256 + k];
    G0[g] = acc;
  } else {  // bid == 4: zero slot array + release flag
    for (int e = tid; e < 4104; e += 256) slots[e] = 0u;
  }
}

// ---------------------------------------------------------------------------
// prep_b: WM = Wrv @ mem_sm (bf16), FM = fc_w-rv @ mem_sm (f32),
//         x f32 [B,T,256] -> bf16 [T, row'(b), 256] with block-local row perm:
//         b = 256q + 16rt + i  ->  row' = rt*64 + q*16 + i
// ---------------------------------------------------------------------------
__global__ void prep_b(const float* __restrict__ x, const float* __restrict__ W_ih,
                       const float* __restrict__ fc_w, const float* __restrict__ mem_sm,
                       bf16* __restrict__ WMg, float* __restrict__ FM,
                       bf16* __restrict__ x_bf) {
  const int bid = blockIdx.x, tid = threadIdx.x;
  if (bid < 128) {
    for (int sub = tid; sub < 4 * 512; sub += 256) {
      int gl = sub >> 9, rn = sub & 511, r = rn >> 7, n = rn & 127;
      int g = bid * 4 + gl;
      const float* wr = W_ih + (size_t)g * 768 + 256 + r * 128;
      float acc = 0.f;
      for (int m = 0; m < 128; ++m) acc += wr[m] * mem_sm[m * 128 + n];
      WMg[(size_t)g * 512 + rn] = (bf16)acc;
    }
  } else if (bid == 128) {
    for (int sub = tid; sub < 2 * 512; sub += 256) {
      int o = sub >> 9, rn = sub & 511, r = rn >> 7, n = rn & 127;
      const float* wr = fc_w + o * 640 + 128 + r * 128;
      float acc = 0.f;
      for (int m = 0; m < 128; ++m) acc += wr[m] * mem_sm[m * 128 + n];
      FM[o * 512 + rn] = acc;
    }
  } else {
    const int lane = tid & 63, wv = tid >> 6;
    for (int rep = 0; rep < 128; ++rep) {
      int rid = (bid - 129) * 512 + wv * 128 + rep;   // rid = b*T + t
      int b = rid >> 7, t = rid & 127;
      int rowp = ((b >> 4) & 15) * 64 + (b >> 8) * 16 + (b & 15);
      const float4 v = *(const float4*)(x + (size_t)rid * 256 + lane * 4);
      bf16x4 o;
      o[0] = (bf16)v.x; o[1] = (bf16)v.y; o[2] = (bf16)v.z; o[3] = (bf16)v.w;
      *(bf16x4*)(x_bf + ((size_t)t * BB + rowp) * 256 + lane * 4) = o;
    }
  }
}

// ---------------------------------------------------------------------------
// persistent main: 256 blocks x 256 threads, ONE grid barrier per step.
//  block (rt = bid>>4, gt = bid&15):
//   rows  R = { rt*16 + i + 256*q : i<16, q<4 }  (64 rows, 4 MFMA m-tiles)
//   gate cols = { c*128 + gt*8 + j : c<4, j<8 }  (i/f/g/o complete -> local pointwise)
//  gates = bias + x@Wx^T + h@Whh^T + hquad@WM^T chained in one accumulator;
//  all 4 m-tiles share the same G tile (hquad rows rt*16..+16 staged in LDS).
//  Barrier: per-block slot store + block0 gather + release flag (no RMW contention).
// ---------------------------------------------------------------------------
__global__ void __launch_bounds__(256, 1) dnc_main(
    const bf16* __restrict__ x_bf, const bf16* __restrict__ WMg,
    const float* __restrict__ bias, const float* __restrict__ G0,
    const float* __restrict__ FM, bf16* __restrict__ hbuf,
    float* __restrict__ hsumG, unsigned* __restrict__ slots,
    const float* __restrict__ W_ih, const float* __restrict__ W_hh,
    const float* __restrict__ fc_w, const float* __restrict__ fc_b,
    float* __restrict__ out) {
  __shared__ bf16 sWx[32][264];    // Wx  (32 owned gate cols) x K=256, +8 pad
  __shared__ bf16 sWhh[32][136];   // Whh x K=128
  __shared__ bf16 sWM[32][520];    // WM  x K=512
  __shared__ bf16 sHq[64][136];    // staged h rows rt*64..+64 (= hquad tile rows rt*16..+16)
  __shared__ float sGates[64][33]; // gate values for local pointwise

  const int bid = blockIdx.x, tid = threadIdx.x;
  const int rt = bid >> 4, gt = bid & 15;
  const int wave = tid >> 6, lane = tid & 63;
  const int l15 = lane & 15, l4 = lane >> 4;
  unsigned* rel = slots + 4096;

  auto gcol = [&](int pos) { return ((pos >> 3) << 7) + gt * 8 + (pos & 7); };

  // one-time weight staging into LDS
  for (int e = tid; e < 32 * 256; e += 256) sWx[e >> 8][e & 255] = (bf16)W_ih[(size_t)gcol(e >> 8) * 768 + (e & 255)];
  for (int e = tid; e < 32 * 128; e += 256) sWhh[e >> 7][e & 127] = (bf16)W_hh[gcol(e >> 7) * 128 + (e & 127)];
  for (int e = tid; e < 32 * 512; e += 256) sWM[e >> 9][e & 511] = WMg[(size_t)gcol(e >> 9) * 512 + (e & 511)];
  __syncthreads();

  const float bv0 = bias[gcol(l15)], bv1 = bias[gcol(16 + l15)];

  // per-thread pointwise cells: row p = tid>>2 (local), cols cc, cc+1 of our 8
  const int p = tid >> 2, cc = (tid & 3) * 2;
  const int grow = rt * 16 + (p & 15) + 256 * (p >> 4);
  float c0s = 0.f, c1s = 0.f, hs0 = 0.f, hs1 = 0.f;

  f32x4 acc0, acc1;

  auto xpart = [&](int t) {
    acc0 = f32x4{bv0, bv0, bv0, bv0};
    acc1 = f32x4{bv1, bv1, bv1, bv1};
    const bf16* xr = x_bf + ((size_t)t * BB + rt * 64 + wave * 16 + l15) * 256 + l4 * 8;
#pragma unroll
    for (int kk = 0; kk < 8; ++kk) {
      bf16x8 a  = *(const bf16x8*)(xr + kk * 32);
      bf16x8 w0 = *(const bf16x8*)&sWx[l15][kk * 32 + l4 * 8];
      bf16x8 w1 = *(const bf16x8*)&sWx[16 + l15][kk * 32 + l4 * 8];
      acc0 = __builtin_amdgcn_mfma_f32_16x16x32_bf16(a, w0, acc0, 0, 0, 0);
      acc1 = __builtin_amdgcn_mfma_f32_16x16x32_bf16(a, w1, acc1, 0, 0, 0);
    }
  };

  auto hpart = [&]() {
    // stage h rows rt*64..+64 into LDS (shared A of the WM GEMM for all 4 m-tiles)
#pragma unroll
    for (int pass = 0; pass < 4; ++pass) {
      int row = (tid >> 4) + 16 * pass, seg = tid & 15;
      bf16x8 v = ld_bf16x8_coh(hbuf + (size_t)(rt * 64 + row) * 128 + seg * 8);
      *(bf16x8*)&sHq[row][seg * 8] = v;
    }
    // h @ Whh^T : A rows = h[rt*16 + i + 256*wave]
    const bf16* hr = hbuf + (size_t)(rt * 16 + l15 + 256 * wave) * 128 + l4 * 8;
#pragma unroll
    for (int kk = 0; kk < 4; ++kk) {
      bf16x8 a  = ld_bf16x8_coh(hr + kk * 32);
      bf16x8 w0 = *(const bf16x8*)&sWhh[l15][kk * 32 + l4 * 8];
      bf16x8 w1 = *(const bf16x8*)&sWhh[16 + l15][kk * 32 + l4 * 8];
      acc0 = __builtin_amdgcn_mfma_f32_16x16x32_bf16(a, w0, acc0, 0, 0, 0);
      acc1 = __builtin_amdgcn_mfma_f32_16x16x32_bf16(a, w1, acc1, 0, 0, 0);
    }
    __syncthreads();  // sHq ready
    // hquad @ WM^T : A row i = hquad[rt*16+i] = sHq rows 4i..4i+4
#pragma unroll
    for (int kk = 0; kk < 16; ++kk) {
      bf16x8 a  = *(const bf16x8*)&sHq[4 * l15 + (kk >> 2)][(kk & 3) * 32 + l4 * 8];
      bf16x8 w0 = *(const bf16x8*)&sWM[l15][kk * 32 + l4 * 8];
      bf16x8 w1 = *(const bf16x8*)&sWM[16 + l15][kk * 32 + l4 * 8];
      acc0 = __builtin_amdgcn_mfma_f32_16x16x32_bf16(a, w0, acc0, 0, 0, 0);
      acc1 = __builtin_amdgcn_mfma_f32_16x16x32_bf16(a, w1, acc1, 0, 0, 0);
    }
  };

  auto pw = [&](bool add_g0) {
    // C/D layout: row = l4*4+r, col = l15 ; local row = wave*16 + row
    int prow = wave * 16 + l4 * 4;
#pragma unroll
    for (int r = 0; r < 4; ++r) {
      sGates[prow + r][l15]      = acc0[r];
      sGates[prow + r][16 + l15] = acc1[r];
    }
    __syncthreads();
    float gi0 = sGates[p][cc],      gi1 = sGates[p][cc + 1];
    float gf0 = sGates[p][8 + cc],  gf1 = sGates[p][9 + cc];
    float gg0 = sGates[p][16 + cc], gg1 = sGates[p][17 + cc];
    float go0 = sGates[p][24 + cc], go1 = sGates[p][25 + cc];
    if (add_g0) {
      int cb = gt * 8 + cc;
      gi0 += G0[cb];       gi1 += G0[cb + 1];
      gf0 += G0[128 + cb]; gf1 += G0[129 + cb];
      gg0 += G0[256 + cb]; gg1 += G0[257 + cb];
      go0 += G0[384 + cb]; go1 += G0[385 + cb];
    }
    c0s = sigmoidf_(gf0) * c0s + sigmoidf_(gi0) * tanhf(gg0);
    c1s = sigmoidf_(gf1) * c1s + sigmoidf_(gi1) * tanhf(gg1);
    float h0 = sigmoidf_(go0) * tanhf(c0s);
    float h1 = sigmoidf_(go1) * tanhf(c1s);
    hs0 += h0; hs1 += h1;
    union { bf16 h[2]; unsigned u; } pk;
    pk.h[0] = (bf16)h0; pk.h[1] = (bf16)h1;
    st_u32_coh((unsigned*)(hbuf + (size_t)grow * 128 + gt * 8 + cc), pk.u);
  };

  auto commit = [&](unsigned gen) {
    asm volatile("s_waitcnt vmcnt(0)" ::: "memory");  // every wave drains its stores
    __syncthreads();
    if (tid == 0) st_u32_coh(slots + bid * 16, gen);
  };
  auto gridwait = [&](unsigned gen) {
    if (bid == 0) {
      while (ld_u32_coh(slots + tid * 16) < gen) __builtin_amdgcn_s_sleep(1);
      __syncthreads();
      if (tid == 0) st_u32_coh(rel, gen);
    } else {
      if (tid == 0) {
        while (ld_u32_coh(rel) < gen) __builtin_amdgcn_s_sleep(1);
      }
    }
    __syncthreads();
  };

  // ---- timeline: one barrier per step -------------------------------------
  xpart(0);
  pw(true);          // t=0: h(-1)=0, G-path = precomputed G0
  commit(1);
  for (int t = 1; t < TT; ++t) {
    xpart(t);        // overlaps the barrier wait (x-only, no h dependency)
    gridwait(t);     // h(t-1) visible
    hpart();
    pw(false);
    commit(t + 1);
  }
  // epilogue: hsum -> global, barrier, fused mean+projection
  st_f32x2_coh(hsumG + (size_t)grow * 128 + gt * 8 + cc, hs0, hs1);
  commit(200);
  gridwait(200);
  {
    int row = bid * 4 + wave;
    const float* hsr = hsumG + (size_t)row * 128;
    const float* hqr = hsumG + (size_t)(row & 255) * 512;
    float s0 = 0.f, s1 = 0.f;
    for (int k = lane; k < 128; k += 64) { float v = ld_f32_coh(hsr + k); s0 += v * fc_w[k]; s1 += v * fc_w[640 + k]; }
    for (int k = lane; k < 512; k += 64) { float v = ld_f32_coh(hqr + k); s0 += v * FM[k]; s1 += v * FM[512 + k]; }
    for (int off = 32; off > 0; off >>= 1) { s0 += __shfl_down(s0, off); s1 += __shfl_down(s1, off); }
    if (lane == 0) {
      out[row * 2 + 0] = s0 * (1.f / 128.f) + fc_b[0];
      out[row * 2 + 1] = s1 * (1.f / 128.f) + fc_b[1];
    }
  }
}

// ---------------------------------------------------------------------------
extern "C" void kernel_launch(void* const* d_in, const int* in_sizes, int n_in,
                              void* d_out, int out_size, void* d_ws, size_t ws_size,
                              hipStream_t stream) {
  const float* x      = (const float*)d_in[0];
  const float* memory = (const float*)d_in[1];
  const float* rv0    = (const float*)d_in[2];
  const float* W_ih   = (const float*)d_in[3];
  const float* W_hh   = (const float*)d_in[4];
  const float* b_ih   = (const float*)d_in[5];
  const float* b_hh   = (const float*)d_in[6];
  const float* fc_w   = (const float*)d_in[7];
  const float* fc_b   = (const float*)d_in[8];
  float* out = (float*)d_out;
  char* ws = (char*)d_ws;

  bf16*     x_bf   = (bf16*)ws;                     // 67,108,864 B
  bf16*     WMg    = (bf16*)(ws + 67108864);        //    524,288
  float*    mem_sm = (float*)(ws + 67633152);       //     65,536
  float*    bias   = (float*)(ws + 67698688);       //      2,048
  float*    G0     = (float*)(ws + 67700736);       //      2,048
  float*    FM     = (float*)(ws + 67702784);       //      4,096
  bf16*     hbuf   = (bf16*)(ws + 67706880);        //    262,144
  unsigned* slots  = (unsigned*)(ws + 67969024);    //     16,416 (slots + rel)
  float*    hsumG  = (float*)(ws + 68000768);       //    524,288

  prep_a<<<5, 256, 0, stream>>>(memory, b_ih, b_hh, rv0, W_ih, mem_sm, bias, G0, slots);
  prep_b<<<385, 256, 0, stream>>>(x, W_ih, fc_w, mem_sm, WMg, FM, x_bf);
  dnc_main<<<NBLK, 256, 0, stream>>>(x_bf, WMg, bias, G0, FM, hbuf, hsumG, slots,
                                     W_ih, W_hh, fc_w, fc_b, out);
}

// Round 4
// 842.860 us; speedup vs baseline: 6.5055x; 1.1991x over previous
//
#include <hip/hip_runtime.h>

#define BB 1024
#define TT 128
#define NBLK 256

using bf16   = __bf16;
using bf16x8 = __attribute__((ext_vector_type(8))) bf16;
using bf16x4 = __attribute__((ext_vector_type(4))) bf16;
using f32x4  = __attribute__((ext_vector_type(4))) float;

__device__ __forceinline__ float fsig(float x) {
  return __builtin_amdgcn_rcpf(1.f + __expf(-x));
}
__device__ __forceinline__ float ftanh(float x) {
  return 2.f * __builtin_amdgcn_rcpf(1.f + __expf(-2.f * x)) - 1.f;
}

// ---- coherent (cross-XCD, IF$-served) load/store helpers -------------------
__device__ __forceinline__ void st_u32_coh(unsigned* p, unsigned v) {
  __hip_atomic_store(p, v, __ATOMIC_RELAXED, __HIP_MEMORY_SCOPE_AGENT);
}
__device__ __forceinline__ unsigned ld_u32_coh(const unsigned* p) {
  return __hip_atomic_load((unsigned*)p, __ATOMIC_RELAXED, __HIP_MEMORY_SCOPE_AGENT);
}
__device__ __forceinline__ float ld_f32_coh(const float* p) {
  return __hip_atomic_load((float*)p, __ATOMIC_RELAXED, __HIP_MEMORY_SCOPE_AGENT);
}
__device__ __forceinline__ void st_f32_coh(float* p, float v) {
  __hip_atomic_store(p, v, __ATOMIC_RELAXED, __HIP_MEMORY_SCOPE_AGENT);
}
__device__ __forceinline__ void st_u16_coh(unsigned short* p, unsigned short v) {
  __hip_atomic_store(p, v, __ATOMIC_RELAXED, __HIP_MEMORY_SCOPE_AGENT);
}
__device__ __forceinline__ bf16x8 ld_bf16x8_coh(const bf16* p) {
  union { unsigned long long u[2]; bf16x8 v; } c;
  c.u[0] = __hip_atomic_load((unsigned long long*)p, __ATOMIC_RELAXED, __HIP_MEMORY_SCOPE_AGENT);
  c.u[1] = __hip_atomic_load((unsigned long long*)(p + 4), __ATOMIC_RELAXED, __HIP_MEMORY_SCOPE_AGENT);
  return c.v;
}

// ---------------------------------------------------------------------------
// prep_a: x f32 [B,T,256] -> bf16 [T,row'(b),256] (2048 blocks), softmax,
//         bias, G0, zero slots
// ---------------------------------------------------------------------------
__global__ void prep_a(const float* __restrict__ x, const float* __restrict__ mem,
                       const float* __restrict__ b_ih, const float* __restrict__ b_hh,
                       const float* __restrict__ rv0, const float* __restrict__ W_ih,
                       bf16* __restrict__ x_bf, float* __restrict__ mem_sm,
                       float* __restrict__ bias, float* __restrict__ G0,
                       unsigned* __restrict__ slots) {
  const int bid = blockIdx.x, tid = threadIdx.x;
  if (bid < 2048) {
    const int lane = tid & 63, wv = tid >> 6;
    const int wg = bid * 4 + wv;  // 0..8191
#pragma unroll 4
    for (int r = 0; r < 16; ++r) {
      int rid = wg + r * 8192;            // rid = b*T + t
      int b = rid >> 7, t = rid & 127;
      int rowp = ((b >> 4) & 15) * 64 + (b >> 8) * 16 + (b & 15);
      const float4 v = *(const float4*)(x + (size_t)rid * 256 + lane * 4);
      bf16x4 o;
      o[0] = (bf16)v.x; o[1] = (bf16)v.y; o[2] = (bf16)v.z; o[3] = (bf16)v.w;
      *(bf16x4*)(x_bf + ((size_t)t * BB + rowp) * 256 + lane * 4) = o;
    }
  } else if (bid == 2048) {
    __shared__ float sM[128 * 128];
    for (int e = tid; e < 16384; e += 256) sM[e] = mem[e];
    __syncthreads();
    if (tid < 128) {
      float mx = -1e30f;
      for (int m = 0; m < 128; ++m) mx = fmaxf(mx, sM[m * 128 + tid]);
      float s = 0.f;
      for (int m = 0; m < 128; ++m) s += __expf(sM[m * 128 + tid] - mx);
      float inv = 1.f / s;
      for (int m = 0; m < 128; ++m) mem_sm[m * 128 + tid] = __expf(sM[m * 128 + tid] - mx) * inv;
    }
  } else if (bid == 2049) {
    for (int e = tid; e < 512; e += 256) bias[e] = b_ih[e] + b_hh[e];
  } else if (bid < 2052) {
    int g = (bid - 2050) * 256 + tid;  // 0..511
    float acc = 0.f;
    for (int k = 0; k < 512; ++k) acc += rv0[k] * W_ih[(size_t)g * 768 + 256 + k];
    G0[g] = acc;
  } else {
    for (int e = tid; e < 4096; e += 256) slots[e] = 0u;
  }
}

// ---------------------------------------------------------------------------
// prep_b: WM[g][r*128+n] = sum_m W_ih[g][256+r*128+m]*mem_sm[m][n]  (512 blocks)
//         FM (block 512)
// ---------------------------------------------------------------------------
__global__ void prep_b(const float* __restrict__ W_ih, const float* __restrict__ fc_w,
                       const float* __restrict__ mem_sm,
                       bf16* __restrict__ WMg, float* __restrict__ FM) {
  const int bid = blockIdx.x, tid = threadIdx.x;
  if (bid < 512) {
    __shared__ float sW[512];
    const int g = bid;
    for (int e = tid; e < 512; e += 256) sW[e] = W_ih[(size_t)g * 768 + 256 + e];
    __syncthreads();
    const int r = tid >> 6, n0 = (tid & 63) * 2;
    float a0 = 0.f, a1 = 0.f;
    const float* wr = sW + r * 128;
#pragma unroll 4
    for (int m = 0; m < 128; ++m) {
      float2 ms = *(const float2*)(mem_sm + m * 128 + n0);
      a0 += wr[m] * ms.x;
      a1 += wr[m] * ms.y;
    }
    union { bf16 h[2]; unsigned u; } pk;
    pk.h[0] = (bf16)a0; pk.h[1] = (bf16)a1;
    *(unsigned*)(WMg + (size_t)g * 512 + r * 128 + n0) = pk.u;
  } else {
    for (int sub = tid; sub < 2 * 512; sub += 256) {
      int o = sub >> 9, rn = sub & 511, rr = rn >> 7, n = rn & 127;
      const float* wr = fc_w + o * 640 + 128 + rr * 128;
      float acc = 0.f;
      for (int m = 0; m < 128; ++m) acc += wr[m] * mem_sm[m * 128 + n];
      FM[o * 512 + rn] = acc;
    }
  }
}

// ---------------------------------------------------------------------------
// persistent main: 256 blocks x 256 threads, one single-hop barrier per step,
// double-buffered h, pointwise in MFMA register layout (shfl_xor), conflict-free
// hquad-major LDS staging.
// ---------------------------------------------------------------------------
__global__ void __launch_bounds__(256, 1) dnc_main(
    const bf16* __restrict__ x_bf, const bf16* __restrict__ WMg,
    const float* __restrict__ bias, const float* __restrict__ G0,
    const float* __restrict__ FM, bf16* __restrict__ hbuf0, bf16* __restrict__ hbuf1,
    float* __restrict__ hsumG, unsigned* __restrict__ slots,
    const float* __restrict__ W_ih, const float* __restrict__ W_hh,
    const float* __restrict__ fc_w, const float* __restrict__ fc_b,
    float* __restrict__ out) {
  __shared__ bf16 sWx[32][264];    // Wx  (32 owned gate cols) x K=256, 33 granules (odd)
  __shared__ bf16 sWhh[32][136];   // 17 granules (odd)
  __shared__ bf16 sWM[32][520];    // 65 granules (odd)
  __shared__ bf16 sHq[16][520];    // hquad-major staged tile, 65 granules (odd)

  const int bid = blockIdx.x, tid = threadIdx.x;
  const int rt = bid >> 4, gt = bid & 15;
  const int wave = tid >> 6, lane = tid & 63;
  const int l15 = lane & 15, l4 = lane >> 4;

  auto gcol = [&](int pos) { return ((pos >> 3) << 7) + gt * 8 + (pos & 7); };

  // one-time weight staging into LDS
  for (int e = tid; e < 32 * 256; e += 256) sWx[e >> 8][e & 255] = (bf16)W_ih[(size_t)gcol(e >> 8) * 768 + (e & 255)];
  for (int e = tid; e < 32 * 128; e += 256) sWhh[e >> 7][e & 127] = (bf16)W_hh[gcol(e >> 7) * 128 + (e & 127)];
  for (int e = tid; e < 32 * 512; e += 256) sWM[e >> 9][e & 511] = WMg[(size_t)gcol(e >> 9) * 512 + (e & 511)];
  __syncthreads();

  const float bv0 = bias[gcol(l15)], bv1 = bias[gcol(16 + l15)];

  // pointwise cell ownership (register layout): lane(l4, j) j<8 -> rows l4*4+{0,1};
  // lane(l4, j+8) -> rows l4*4+{2,3}; col = gt*8+j; tile = wave.
  const bool lo = (l15 < 8);
  const int j = l15 & 7;
  const int rb = lo ? 0 : 2;
  float cst[2] = {0.f, 0.f}, hsum[2] = {0.f, 0.f};
  int growp[2];
#pragma unroll
  for (int k = 0; k < 2; ++k) growp[k] = rt * 16 + (l4 * 4 + rb + k) + 256 * wave;

  f32x4 acc0, acc1;

  auto xpart = [&](int t) {
    acc0 = f32x4{bv0, bv0, bv0, bv0};
    acc1 = f32x4{bv1, bv1, bv1, bv1};
    const bf16* xr = x_bf + ((size_t)t * BB + rt * 64 + wave * 16 + l15) * 256 + l4 * 8;
#pragma unroll
    for (int kk = 0; kk < 8; ++kk) {
      bf16x8 a  = *(const bf16x8*)(xr + kk * 32);
      bf16x8 w0 = *(const bf16x8*)&sWx[l15][kk * 32 + l4 * 8];
      bf16x8 w1 = *(const bf16x8*)&sWx[16 + l15][kk * 32 + l4 * 8];
      acc0 = __builtin_amdgcn_mfma_f32_16x16x32_bf16(a, w0, acc0, 0, 0, 0);
      acc1 = __builtin_amdgcn_mfma_f32_16x16x32_bf16(a, w1, acc1, 0, 0, 0);
    }
  };

  auto hpart = [&](const bf16* hrd) {
    // Whh A-rows into registers first (critical for early MFMA issue)
    bf16x8 ha[4];
    const bf16* hr = hrd + (size_t)(rt * 16 + l15 + 256 * wave) * 128 + l4 * 8;
#pragma unroll
    for (int kk = 0; kk < 4; ++kk) ha[kk] = ld_bf16x8_coh(hr + kk * 32);
    // stage h rows rt*64..+64 as hquad-major tile (row j holds h rows 4j..4j+3)
#pragma unroll
    for (int pass = 0; pass < 4; ++pass) {
      int row = (tid >> 4) + 16 * pass, seg = tid & 15;
      bf16x8 v = ld_bf16x8_coh(hrd + (size_t)(rt * 64 + row) * 128 + seg * 8);
      *(bf16x8*)&sHq[row >> 2][(row & 3) * 128 + seg * 8] = v;
    }
#pragma unroll
    for (int kk = 0; kk < 4; ++kk) {
      bf16x8 w0 = *(const bf16x8*)&sWhh[l15][kk * 32 + l4 * 8];
      bf16x8 w1 = *(const bf16x8*)&sWhh[16 + l15][kk * 32 + l4 * 8];
      acc0 = __builtin_amdgcn_mfma_f32_16x16x32_bf16(ha[kk], w0, acc0, 0, 0, 0);
      acc1 = __builtin_amdgcn_mfma_f32_16x16x32_bf16(ha[kk], w1, acc1, 0, 0, 0);
    }
    __syncthreads();  // sHq ready
#pragma unroll
    for (int kk = 0; kk < 16; ++kk) {
      bf16x8 a  = *(const bf16x8*)&sHq[l15][kk * 32 + l4 * 8];
      bf16x8 w0 = *(const bf16x8*)&sWM[l15][kk * 32 + l4 * 8];
      bf16x8 w1 = *(const bf16x8*)&sWM[16 + l15][kk * 32 + l4 * 8];
      acc0 = __builtin_amdgcn_mfma_f32_16x16x32_bf16(a, w0, acc0, 0, 0, 0);
      acc1 = __builtin_amdgcn_mfma_f32_16x16x32_bf16(a, w1, acc1, 0, 0, 0);
    }
  };

  auto pw = [&](bool add_g0, bf16* hwr) {
    // acc0[r]: lane(l4,j)=i[row,j], lane(l4,j+8)=f[row,j]; acc1: g/o. row=l4*4+r.
    float o0[4], o1[4];
#pragma unroll
    for (int r = 0; r < 4; ++r) {
      o0[r] = __shfl_xor(acc0[r], 8);
      o1[r] = __shfl_xor(acc1[r], 8);
    }
    float g0i = 0.f, g0f = 0.f, g0g = 0.f, g0o = 0.f;
    if (add_g0) {
      int cb = gt * 8 + j;
      g0i = G0[cb]; g0f = G0[128 + cb]; g0g = G0[256 + cb]; g0o = G0[384 + cb];
    }
#pragma unroll
    for (int k = 0; k < 2; ++k) {
      int r = rb + k;
      float gi = (lo ? acc0[r] : o0[r]) + g0i;
      float gf = (lo ? o0[r] : acc0[r]) + g0f;
      float gg = (lo ? acc1[r] : o1[r]) + g0g;
      float go = (lo ? o1[r] : acc1[r]) + g0o;
      cst[k] = fsig(gf) * cst[k] + fsig(gi) * ftanh(gg);
      float h = fsig(go) * ftanh(cst[k]);
      hsum[k] += h;
      union { bf16 b; unsigned short u; } cv; cv.b = (bf16)h;
      st_u16_coh((unsigned short*)(hwr + (size_t)growp[k] * 128 + gt * 8 + j), cv.u);
    }
  };

  auto commit = [&](unsigned gen) {
    asm volatile("s_waitcnt vmcnt(0)" ::: "memory");
    __syncthreads();
    if (tid == 0) st_u32_coh(slots + bid * 16, gen);
  };
  auto gridwait = [&](unsigned gen) {
    // single-hop all-to-all: thread t polls block t's slot
    while (ld_u32_coh(slots + tid * 16) < gen) {}
    __syncthreads();
  };

  // ---- timeline: one barrier per step, double-buffered h ------------------
  xpart(0);
  pw(true, hbuf0);   // h_0 -> buf0 (h(-1)=0; G-path = G0)
  commit(1);
  for (int t = 1; t < TT; ++t) {
    xpart(t);                              // h-independent, overlaps stragglers
    gridwait(t);                           // all blocks committed h_{t-1}
    hpart((t & 1) ? hbuf0 : hbuf1);        // read h_{t-1} from buf[(t-1)&1]
    pw(false, (t & 1) ? hbuf1 : hbuf0);    // write h_t to buf[t&1]
    commit(t + 1);
  }
  // epilogue: hsum -> global, barrier, fused mean+projection
#pragma unroll
  for (int k = 0; k < 2; ++k)
    st_f32_coh(hsumG + (size_t)growp[k] * 128 + gt * 8 + j, hsum[k]);
  commit(TT + 1);
  gridwait(TT + 1);
  {
    int row = bid * 4 + wave;
    const float* hsr = hsumG + (size_t)row * 128;
    const float* hqr = hsumG + (size_t)(row & 255) * 512;
    float s0 = 0.f, s1 = 0.f;
    for (int k = lane; k < 128; k += 64) { float v = ld_f32_coh(hsr + k); s0 += v * fc_w[k]; s1 += v * fc_w[640 + k]; }
    for (int k = lane; k < 512; k += 64) { float v = ld_f32_coh(hqr + k); s0 += v * FM[k]; s1 += v * FM[512 + k]; }
    for (int off = 32; off > 0; off >>= 1) { s0 += __shfl_down(s0, off); s1 += __shfl_down(s1, off); }
    if (lane == 0) {
      out[row * 2 + 0] = s0 * (1.f / 128.f) + fc_b[0];
      out[row * 2 + 1] = s1 * (1.f / 128.f) + fc_b[1];
    }
  }
}

// ---------------------------------------------------------------------------
extern "C" void kernel_launch(void* const* d_in, const int* in_sizes, int n_in,
                              void* d_out, int out_size, void* d_ws, size_t ws_size,
                              hipStream_t stream) {
  const float* x      = (const float*)d_in[0];
  const float* memory = (const float*)d_in[1];
  const float* rv0    = (const float*)d_in[2];
  const float* W_ih   = (const float*)d_in[3];
  const float* W_hh   = (const float*)d_in[4];
  const float* b_ih   = (const float*)d_in[5];
  const float* b_hh   = (const float*)d_in[6];
  const float* fc_w   = (const float*)d_in[7];
  const float* fc_b   = (const float*)d_in[8];
  float* out = (float*)d_out;
  char* ws = (char*)d_ws;

  bf16*     x_bf   = (bf16*)ws;                     // 67,108,864 B
  bf16*     WMg    = (bf16*)(ws + 67108864);        //    524,288
  float*    mem_sm = (float*)(ws + 67633152);       //     65,536
  float*    bias   = (float*)(ws + 67698688);       //      2,048
  float*    G0     = (float*)(ws + 67700736);       //      2,048
  float*    FM     = (float*)(ws + 67702784);       //      4,096
  bf16*     hbuf0  = (bf16*)(ws + 67706880);        //    262,144
  bf16*     hbuf1  = (bf16*)(ws + 67969024);        //    262,144
  unsigned* slots  = (unsigned*)(ws + 68231168);    //     16,384
  float*    hsumG  = (float*)(ws + 68247552);       //    524,288

  prep_a<<<2053, 256, 0, stream>>>(x, memory, b_ih, b_hh, rv0, W_ih,
                                   x_bf, mem_sm, bias, G0, slots);
  prep_b<<<513, 256, 0, stream>>>(W_ih, fc_w, mem_sm, WMg, FM);
  dnc_main<<<NBLK, 256, 0, stream>>>(x_bf, WMg, bias, G0, FM, hbuf0, hbuf1, hsumG, slots,
                                     W_ih, W_hh, fc_w, fc_b, out);
}